// Round 1
// baseline (329.179 us; speedup 1.0000x reference)
//
#include <hip/hip_runtime.h>
#include <stdint.h>

#define B_ 8
#define S_ 1024
#define H_ 768
#define NH_ 12
#define HD_ 64
#define M_ (B_*S_)   // 8192 tokens

typedef __attribute__((ext_vector_type(8))) short short8;
typedef __attribute__((ext_vector_type(4))) float floatx4;

#define MFMA16(a,b,c) __builtin_amdgcn_mfma_f32_16x16x32_bf16((a),(b),(c),0,0,0)

__device__ __forceinline__ ushort f2bf(float x){
    union { float f; unsigned u; } v; v.f = x;
    unsigned r = (v.u + 0x7fffu + ((v.u >> 16) & 1u)) >> 16;
    return (ushort)r;
}

__device__ __forceinline__ void async16(const ushort* g, ushort* l){
    __builtin_amdgcn_global_load_lds(
        (const __attribute__((address_space(1))) unsigned int*)g,
        (__attribute__((address_space(3))) unsigned int*)l, 16, 0, 0);
}

// ---------------- f32 -> bf16 cast ----------------
__global__ __launch_bounds__(256, 8) void cvt_bf16(const float* __restrict__ s,
                                                   ushort* __restrict__ d, int n4){
    int i = blockIdx.x*256 + threadIdx.x;
    if (i >= n4) return;
    float4 f = ((const float4*)s)[i];
    ushort4 u;
    u.x = f2bf(f.x); u.y = f2bf(f.y); u.z = f2bf(f.z); u.w = f2bf(f.w);
    ((ushort4*)d)[i] = u;
}

// ---------------- GEMM: C[M,N] = A[M,K] @ B[N,K]^T + bias ----------------
// mode 0: bf16 out [M,768]   (Q, K)
// mode 1: bf16 out transposed per head: Vt[(b*12+h)*64+d][1024] (V)
// mode 2: f32 out [M,768]    (O-projection)
__global__ __launch_bounds__(256, 2) void gemm_bt(
    const ushort* __restrict__ A, const ushort* __restrict__ Bw,
    const float* __restrict__ bias, ushort* __restrict__ obf,
    float* __restrict__ of32, int mode)
{
    __shared__ ushort lA[128*32];
    __shared__ ushort lB[128*32];
    const int K = H_;
    int tid  = threadIdx.x;
    int lane = tid & 63, wave = tid >> 6;
    int m0 = blockIdx.x * 128, n0 = blockIdx.y * 128;
    int wm = (wave >> 1) * 64, wn = (wave & 1) * 64;

    floatx4 acc[4][4];
    #pragma unroll
    for (int mt=0;mt<4;mt++)
        #pragma unroll
        for (int nt=0;nt<4;nt++)
            acc[mt][nt] = (floatx4){0.f,0.f,0.f,0.f};

    int ldrow = tid >> 2;          // 0..63
    int ldcol = (tid & 3) * 8;     // k element offset
    const ushort* Ap = A  + (size_t)(m0 + ldrow) * K + ldcol;
    const ushort* Bp = Bw + (size_t)(n0 + ldrow) * K + ldcol;
    // lds byte offset == tid*16 (+ half offset): wave-uniform base + lane*16 as required
    ushort* lA0 = &lA[ldrow*32 + ldcol];
    ushort* lA1 = &lA[(ldrow+64)*32 + ldcol];
    ushort* lB0 = &lB[ldrow*32 + ldcol];
    ushort* lB1 = &lB[(ldrow+64)*32 + ldcol];

    int fr = lane & 15, fq = (lane >> 4) * 8;

    for (int k0 = 0; k0 < K; k0 += 32){
        async16(Ap + k0,          lA0);
        async16(Ap + 64*K + k0,   lA1);
        async16(Bp + k0,          lB0);
        async16(Bp + 64*K + k0,   lB1);
        __syncthreads();
        short8 af[4], bfr[4];
        #pragma unroll
        for (int t=0;t<4;t++){
            af[t]  = *(const short8*)&lA[(wm + t*16 + fr)*32 + fq];
            bfr[t] = *(const short8*)&lB[(wn + t*16 + fr)*32 + fq];
        }
        #pragma unroll
        for (int mt=0;mt<4;mt++)
            #pragma unroll
            for (int nt=0;nt<4;nt++)
                acc[mt][nt] = MFMA16(af[mt], bfr[nt], acc[mt][nt]);
        __syncthreads();
    }

    float bv_[4];
    #pragma unroll
    for (int nt=0;nt<4;nt++) bv_[nt] = bias[n0 + wn + nt*16 + fr];

    // C/D layout: col = lane&15, row = (lane>>4)*4 + reg
    if (mode == 0){
        #pragma unroll
        for (int mt=0;mt<4;mt++){
            int rb = m0 + wm + mt*16 + (lane>>4)*4;
            #pragma unroll
            for (int nt=0;nt<4;nt++){
                int col = n0 + wn + nt*16 + fr;
                #pragma unroll
                for (int r=0;r<4;r++)
                    obf[(size_t)(rb + r)*H_ + col] = f2bf(acc[mt][nt][r] + bv_[nt]);
            }
        }
    } else if (mode == 1){
        #pragma unroll
        for (int mt=0;mt<4;mt++){
            int tok = m0 + wm + mt*16 + (lane>>4)*4;
            int b = tok >> 10, q = tok & 1023;
            #pragma unroll
            for (int nt=0;nt<4;nt++){
                int n = n0 + wn + nt*16 + fr;
                int h = n >> 6, dd = n & 63;
                ushort4 u;
                u.x = f2bf(acc[mt][nt][0] + bv_[nt]);
                u.y = f2bf(acc[mt][nt][1] + bv_[nt]);
                u.z = f2bf(acc[mt][nt][2] + bv_[nt]);
                u.w = f2bf(acc[mt][nt][3] + bv_[nt]);
                *(ushort4*)&obf[((size_t)((b*NH_ + h)*HD_ + dd))*S_ + q] = u;
            }
        }
    } else {
        #pragma unroll
        for (int mt=0;mt<4;mt++){
            int rb = m0 + wm + mt*16 + (lane>>4)*4;
            #pragma unroll
            for (int nt=0;nt<4;nt++){
                int col = n0 + wn + nt*16 + fr;
                #pragma unroll
                for (int r=0;r<4;r++)
                    of32[(size_t)(rb + r)*H_ + col] = acc[mt][nt][r] + bv_[nt];
            }
        }
    }
}

// ---------------- flash attention ----------------
// grid: B*NH*16 blocks; block = (b, h, 64 q-rows); 4 waves x 16 q-rows each
__global__ __launch_bounds__(256, 3) void attn(
    const ushort* __restrict__ Q, const ushort* __restrict__ Kc,
    const ushort* __restrict__ Vt, const float* __restrict__ mask,
    ushort* __restrict__ ctx)
{
    __shared__ ushort lK[64*72];       // [key][d], pad 72 (144B rows, 16B aligned)
    __shared__ ushort lV[64*72];       // [d][key], pad 72
    __shared__ ushort lP[4][16*72];    // per-wave P round-trip
    __shared__ float  lmask[S_];

    int bid = blockIdx.x;
    int qt = bid & 15;
    int h  = (bid >> 4) % NH_;
    int b  = bid / (16*NH_);

    int tid  = threadIdx.x;
    int lane = tid & 63, wave = tid >> 6;
    int fr = lane & 15, fq8 = (lane >> 4) * 8;

    for (int i = tid; i < S_; i += 256)
        lmask[i] = (1.0f - mask[b*S_ + i]) * -10000.0f;

    // Q A-fragments (m=lane&15, k=quad*8+j), HD=64 -> 2 frags
    const ushort* Qp = Q + (size_t)(b*S_ + qt*64 + wave*16 + fr)*H_ + h*HD_;
    short8 qf0 = *(const short8*)(Qp + fq8);
    short8 qf1 = *(const short8*)(Qp + 32 + fq8);

    floatx4 O[4];
    #pragma unroll
    for (int nt=0;nt<4;nt++) O[nt] = (floatx4){0.f,0.f,0.f,0.f};
    float mrun[4], lrun[4];
    #pragma unroll
    for (int r=0;r<4;r++){ mrun[r] = -3.0e38f; lrun[r] = 0.f; }

    int srow = tid >> 3;           // 0..31
    int scol = (tid & 7) * 8;      // element offset
    const ushort* Kp = Kc + (size_t)(b*S_)*H_ + h*HD_;
    const ushort* Vp = Vt + (size_t)(b*NH_ + h)*HD_*S_;

    for (int kt = 0; kt < 16; kt++){
        __syncthreads();   // prior-iter LDS reads done (also covers lmask on iter 0)
        const ushort* gk = Kp + (size_t)(kt*64 + srow)*H_ + scol;
        *(uint4*)&lK[srow*72 + scol]      = *(const uint4*)gk;
        *(uint4*)&lK[(srow+32)*72 + scol] = *(const uint4*)(gk + (size_t)32*H_);
        const ushort* gv = Vp + (size_t)srow*S_ + kt*64 + scol;
        *(uint4*)&lV[srow*72 + scol]      = *(const uint4*)gv;
        *(uint4*)&lV[(srow+32)*72 + scol] = *(const uint4*)(gv + 32*S_);
        __syncthreads();

        // S = Q K^T : 4 key n-tiles x 2 k-frags
        floatx4 s[4];
        #pragma unroll
        for (int nt=0;nt<4;nt++){
            floatx4 a = (floatx4){0.f,0.f,0.f,0.f};
            short8 k0 = *(const short8*)&lK[(nt*16+fr)*72 + fq8];
            short8 k1 = *(const short8*)&lK[(nt*16+fr)*72 + 32 + fq8];
            a = MFMA16(qf0, k0, a);
            a = MFMA16(qf1, k1, a);
            s[nt] = a;
        }
        #pragma unroll
        for (int nt=0;nt<4;nt++){
            float mt_ = lmask[kt*64 + nt*16 + fr];
            #pragma unroll
            for (int r=0;r<4;r++) s[nt][r] = s[nt][r]*0.125f + mt_;
        }
        // online softmax per q-row (row lives in lanes with same lane>>4)
        float mnew[4], alpha[4], rs[4];
        #pragma unroll
        for (int r=0;r<4;r++){
            float mx = fmaxf(fmaxf(s[0][r], s[1][r]), fmaxf(s[2][r], s[3][r]));
            mx = fmaxf(mx, __shfl_xor(mx, 1));
            mx = fmaxf(mx, __shfl_xor(mx, 2));
            mx = fmaxf(mx, __shfl_xor(mx, 4));
            mx = fmaxf(mx, __shfl_xor(mx, 8));
            mnew[r] = fmaxf(mrun[r], mx);
            alpha[r] = __expf(mrun[r] - mnew[r]);
            mrun[r] = mnew[r];
            rs[r] = 0.f;
        }
        #pragma unroll
        for (int nt=0;nt<4;nt++)
            #pragma unroll
            for (int r=0;r<4;r++){
                float p = __expf(s[nt][r] - mnew[r]);
                s[nt][r] = p; rs[r] += p;
            }
        #pragma unroll
        for (int r=0;r<4;r++){
            rs[r] += __shfl_xor(rs[r], 1);
            rs[r] += __shfl_xor(rs[r], 2);
            rs[r] += __shfl_xor(rs[r], 4);
            rs[r] += __shfl_xor(rs[r], 8);
            lrun[r] = lrun[r]*alpha[r] + rs[r];
        }
        #pragma unroll
        for (int nt=0;nt<4;nt++){
            O[nt][0]*=alpha[0]; O[nt][1]*=alpha[1];
            O[nt][2]*=alpha[2]; O[nt][3]*=alpha[3];
        }
        // P: C-layout -> LDS -> A-layout
        ushort* Pw = &lP[wave][0];
        int prow = (lane>>4)*4;
        #pragma unroll
        for (int nt=0;nt<4;nt++)
            #pragma unroll
            for (int r=0;r<4;r++)
                Pw[(prow+r)*72 + nt*16 + fr] = f2bf(s[nt][r]);
        __syncthreads();
        short8 pf0 = *(const short8*)&Pw[fr*72 + fq8];
        short8 pf1 = *(const short8*)&Pw[fr*72 + 32 + fq8];
        // O += P @ V : Vt LDS is [d][key] so B-frag (n=d=lane&15 row, k=key contiguous)
        #pragma unroll
        for (int nt=0;nt<4;nt++){
            short8 v0 = *(const short8*)&lV[(nt*16+fr)*72 + fq8];
            short8 v1 = *(const short8*)&lV[(nt*16+fr)*72 + 32 + fq8];
            O[nt] = MFMA16(pf0, v0, O[nt]);
            O[nt] = MFMA16(pf1, v1, O[nt]);
        }
    }
    float inv[4];
    #pragma unroll
    for (int r=0;r<4;r++) inv[r] = 1.0f / lrun[r];
    ushort* Cp = ctx + (size_t)(b*S_ + qt*64 + wave*16)*H_ + h*HD_;
    #pragma unroll
    for (int nt=0;nt<4;nt++)
        #pragma unroll
        for (int r=0;r<4;r++){
            int row = (lane>>4)*4 + r;
            Cp[(size_t)row*H_ + nt*16 + fr] = f2bf(O[nt][r] * inv[r]);
        }
}

// ---------------- residual + LayerNorm ----------------
__global__ __launch_bounds__(256, 4) void resid_ln(
    const float* __restrict__ proj, const float* __restrict__ hs,
    const float* __restrict__ g, const float* __restrict__ be,
    float* __restrict__ out)
{
    int row = blockIdx.x;
    int tid = threadIdx.x;
    const float* p = proj + (size_t)row*H_;
    const float* x = hs   + (size_t)row*H_;
    float v[3]; float s = 0.f, s2 = 0.f;
    #pragma unroll
    for (int j=0;j<3;j++){
        float t = p[tid + j*256] + x[tid + j*256];
        v[j] = t; s += t; s2 += t*t;
    }
    #pragma unroll
    for (int off=1; off<64; off<<=1){
        s  += __shfl_xor(s,  off);
        s2 += __shfl_xor(s2, off);
    }
    __shared__ float rs[4], rs2[4];
    if ((tid & 63) == 0){ rs[tid>>6] = s; rs2[tid>>6] = s2; }
    __syncthreads();
    s  = rs[0]+rs[1]+rs[2]+rs[3];
    s2 = rs2[0]+rs2[1]+rs2[2]+rs2[3];
    float mu  = s * (1.f/H_);
    float var = s2*(1.f/H_) - mu*mu;
    float rinv = rsqrtf(var + 1e-5f);
    float* o = out + (size_t)row*H_;
    #pragma unroll
    for (int j=0;j<3;j++){
        int c = tid + j*256;
        o[c] = (v[j]-mu)*rinv*g[c] + be[c];
    }
}

extern "C" void kernel_launch(void* const* d_in, const int* in_sizes, int n_in,
                              void* d_out, int out_size, void* d_ws, size_t ws_size,
                              hipStream_t stream)
{
    (void)in_sizes; (void)n_in; (void)out_size; (void)ws_size;
    const float* hs   = (const float*)d_in[0];
    const float* ce   = (const float*)d_in[1];
    const float* mask = (const float*)d_in[2];
    const float* Wq   = (const float*)d_in[3];
    const float* bq   = (const float*)d_in[4];
    const float* Wk   = (const float*)d_in[5];
    const float* bk   = (const float*)d_in[6];
    const float* Wv   = (const float*)d_in[7];
    const float* bv   = (const float*)d_in[8];
    const float* Wo   = (const float*)d_in[9];
    const float* bo   = (const float*)d_in[10];
    const float* lg   = (const float*)d_in[11];
    const float* lb   = (const float*)d_in[12];
    float* out = (float*)d_out;

    char* ws = (char*)d_ws;
    const size_t SZ_ACT = (size_t)M_*H_*2;   // 12,582,912
    const size_t SZ_W   = (size_t)H_*H_*2;   //  1,179,648
    ushort* hsb  = (ushort*)(ws);
    ushort* ceb  = (ushort*)(ws + SZ_ACT);
    ushort* wqb  = (ushort*)(ws + 2*SZ_ACT);
    ushort* wkb  = (ushort*)(ws + 2*SZ_ACT + 1*SZ_W);
    ushort* wvb  = (ushort*)(ws + 2*SZ_ACT + 2*SZ_W);
    ushort* wob  = (ushort*)(ws + 2*SZ_ACT + 3*SZ_W);
    ushort* Qb   = (ushort*)(ws + 2*SZ_ACT + 4*SZ_W);
    ushort* Kb   = (ushort*)(ws + 3*SZ_ACT + 4*SZ_W);
    ushort* Vtb  = (ushort*)(ws + 4*SZ_ACT + 4*SZ_W);
    ushort* ctxb = (ushort*)(ws + 5*SZ_ACT + 4*SZ_W);
    float*  proj = (float*)(ws);  // aliases hsb+ceb (dead after QKV GEMMs); needs 25.2MB
    // total ws use: 6*SZ_ACT + 4*SZ_W = 80,216,064 bytes

    int nact4 = M_*H_/4;   // 1,572,864
    int nw4   = H_*H_/4;   //   147,456
    cvt_bf16<<<dim3((nact4+255)/256), dim3(256), 0, stream>>>(hs, hsb, nact4);
    cvt_bf16<<<dim3((nact4+255)/256), dim3(256), 0, stream>>>(ce, ceb, nact4);
    cvt_bf16<<<dim3((nw4+255)/256),   dim3(256), 0, stream>>>(Wq, wqb, nw4);
    cvt_bf16<<<dim3((nw4+255)/256),   dim3(256), 0, stream>>>(Wk, wkb, nw4);
    cvt_bf16<<<dim3((nw4+255)/256),   dim3(256), 0, stream>>>(Wv, wvb, nw4);
    cvt_bf16<<<dim3((nw4+255)/256),   dim3(256), 0, stream>>>(Wo, wob, nw4);

    dim3 gg(M_/128, H_/128);   // (64, 6)
    gemm_bt<<<gg, dim3(256), 0, stream>>>(hsb, wqb, bq, Qb,  nullptr, 0);
    gemm_bt<<<gg, dim3(256), 0, stream>>>(ceb, wkb, bk, Kb,  nullptr, 0);
    gemm_bt<<<gg, dim3(256), 0, stream>>>(ceb, wvb, bv, Vtb, nullptr, 1);
    attn<<<dim3(B_*NH_*16), dim3(256), 0, stream>>>(Qb, Kb, Vtb, mask, ctxb);
    gemm_bt<<<gg, dim3(256), 0, stream>>>(ctxb, wob, bo, nullptr, proj, 2);
    resid_ln<<<dim3(M_), dim3(256), 0, stream>>>(proj, hs, lg, lb, out);
}

// Round 2
// 239.030 us; speedup vs baseline: 1.3771x; 1.3771x over previous
//
#include <hip/hip_runtime.h>
#include <stdint.h>

#define B_ 8
#define S_ 1024
#define H_ 768
#define NH_ 12
#define HD_ 64
#define M_ (B_*S_)   // 8192 tokens

typedef __attribute__((ext_vector_type(8))) short short8;
typedef __attribute__((ext_vector_type(4))) float floatx4;

#define MFMA16(a,b,c) __builtin_amdgcn_mfma_f32_16x16x32_bf16((a),(b),(c),0,0,0)

__device__ __forceinline__ ushort f2bf(float x){
    union { float f; unsigned u; } v; v.f = x;
    unsigned r = (v.u + 0x7fffu + ((v.u >> 16) & 1u)) >> 16;
    return (ushort)r;
}

__device__ __forceinline__ void async16(const ushort* g, ushort* l){
    __builtin_amdgcn_global_load_lds(
        (const __attribute__((address_space(1))) unsigned int*)g,
        (__attribute__((address_space(3))) unsigned int*)l, 16, 0, 0);
}

// ---------------- fused f32 -> bf16 cast for all 6 tensors ----------------
__global__ __launch_bounds__(256, 8) void cvt_all(
    const float* __restrict__ hs, const float* __restrict__ ce,
    const float* __restrict__ wq, const float* __restrict__ wk,
    const float* __restrict__ wv, const float* __restrict__ wo,
    ushort* __restrict__ hsb, ushort* __restrict__ ceb,
    ushort* __restrict__ wqb, ushort* __restrict__ wkb,
    ushort* __restrict__ wvb, ushort* __restrict__ wob)
{
    const int NA = M_*H_/4;      // 1,572,864 float4s per activation
    const int NW = H_*H_/4;      //   147,456 float4s per weight
    int i = blockIdx.x*256 + threadIdx.x;
    if (i >= 2*NA + 4*NW) return;
    const float* s; ushort* d; int off;
    if (i < NA)            { s = hs; d = hsb; off = i; }
    else if (i < 2*NA)     { s = ce; d = ceb; off = i - NA; }
    else {
        int j = i - 2*NA;
        int wsel = j / NW;
        off = j - wsel*NW;
        s = (wsel==0) ? wq : (wsel==1) ? wk : (wsel==2) ? wv : wo;
        d = (wsel==0) ? wqb : (wsel==1) ? wkb : (wsel==2) ? wvb : wob;
    }
    float4 f = ((const float4*)s)[off];
    ushort4 u;
    u.x = f2bf(f.x); u.y = f2bf(f.y); u.z = f2bf(f.z); u.w = f2bf(f.w);
    ((ushort4*)d)[off] = u;
}

// ---------------- shared GEMM body: C[M,N] = A[M,K] @ B[N,K]^T + bias ------
// mode 0: bf16 out [M,768]; mode 1: Vt[(b*12+h)*64+d][1024]; mode 2: f32 out
__device__ __forceinline__ void gemm_body(
    const ushort* __restrict__ A, const ushort* __restrict__ Bw,
    const float* __restrict__ bias, ushort* __restrict__ obf,
    float* __restrict__ of32, int mode, int bx, int by)
{
    __shared__ ushort lA[128*32];
    __shared__ ushort lB[128*32];
    const int K = H_;
    int tid  = threadIdx.x;
    int lane = tid & 63, wave = tid >> 6;
    int m0 = bx * 128, n0 = by * 128;
    int wm = (wave >> 1) * 64, wn = (wave & 1) * 64;

    floatx4 acc[4][4];
    #pragma unroll
    for (int mt=0;mt<4;mt++)
        #pragma unroll
        for (int nt=0;nt<4;nt++)
            acc[mt][nt] = (floatx4){0.f,0.f,0.f,0.f};

    int ldrow = tid >> 2;
    int ldcol = (tid & 3) * 8;
    const ushort* Ap = A  + (size_t)(m0 + ldrow) * K + ldcol;
    const ushort* Bp = Bw + (size_t)(n0 + ldrow) * K + ldcol;
    ushort* lA0 = &lA[ldrow*32 + ldcol];
    ushort* lA1 = &lA[(ldrow+64)*32 + ldcol];
    ushort* lB0 = &lB[ldrow*32 + ldcol];
    ushort* lB1 = &lB[(ldrow+64)*32 + ldcol];

    int fr = lane & 15, fq = (lane >> 4) * 8;

    for (int k0 = 0; k0 < K; k0 += 32){
        async16(Ap + k0,          lA0);
        async16(Ap + 64*K + k0,   lA1);
        async16(Bp + k0,          lB0);
        async16(Bp + 64*K + k0,   lB1);
        __syncthreads();
        short8 af[4], bfr[4];
        #pragma unroll
        for (int t=0;t<4;t++){
            af[t]  = *(const short8*)&lA[(wm + t*16 + fr)*32 + fq];
            bfr[t] = *(const short8*)&lB[(wn + t*16 + fr)*32 + fq];
        }
        #pragma unroll
        for (int mt=0;mt<4;mt++)
            #pragma unroll
            for (int nt=0;nt<4;nt++)
                acc[mt][nt] = MFMA16(af[mt], bfr[nt], acc[mt][nt]);
        __syncthreads();
    }

    float bv_[4];
    #pragma unroll
    for (int nt=0;nt<4;nt++) bv_[nt] = bias[n0 + wn + nt*16 + fr];

    if (mode == 0){
        #pragma unroll
        for (int mt=0;mt<4;mt++){
            int rb = m0 + wm + mt*16 + (lane>>4)*4;
            #pragma unroll
            for (int nt=0;nt<4;nt++){
                int col = n0 + wn + nt*16 + fr;
                #pragma unroll
                for (int r=0;r<4;r++)
                    obf[(size_t)(rb + r)*H_ + col] = f2bf(acc[mt][nt][r] + bv_[nt]);
            }
        }
    } else if (mode == 1){
        #pragma unroll
        for (int mt=0;mt<4;mt++){
            int tok = m0 + wm + mt*16 + (lane>>4)*4;
            int b = tok >> 10, q = tok & 1023;
            #pragma unroll
            for (int nt=0;nt<4;nt++){
                int n = n0 + wn + nt*16 + fr;
                int h = n >> 6, dd = n & 63;
                ushort4 u;
                u.x = f2bf(acc[mt][nt][0] + bv_[nt]);
                u.y = f2bf(acc[mt][nt][1] + bv_[nt]);
                u.z = f2bf(acc[mt][nt][2] + bv_[nt]);
                u.w = f2bf(acc[mt][nt][3] + bv_[nt]);
                *(ushort4*)&obf[((size_t)((b*NH_ + h)*HD_ + dd))*S_ + q] = u;
            }
        }
    } else {
        #pragma unroll
        for (int mt=0;mt<4;mt++){
            int rb = m0 + wm + mt*16 + (lane>>4)*4;
            #pragma unroll
            for (int nt=0;nt<4;nt++){
                int col = n0 + wn + nt*16 + fr;
                #pragma unroll
                for (int r=0;r<4;r++)
                    of32[(size_t)(rb + r)*H_ + col] = acc[mt][nt][r] + bv_[nt];
            }
        }
    }
}

// fused Q/K/V projection: grid (64, 6, 3)
__global__ __launch_bounds__(256, 3) void gemm_qkv(
    const ushort* __restrict__ hsb, const ushort* __restrict__ ceb,
    const ushort* __restrict__ wqb, const ushort* __restrict__ wkb,
    const ushort* __restrict__ wvb,
    const float* __restrict__ bq, const float* __restrict__ bk,
    const float* __restrict__ bv,
    ushort* __restrict__ Qb, ushort* __restrict__ Kb, ushort* __restrict__ Vtb)
{
    int z = blockIdx.z;
    const ushort* A  = (z==0) ? hsb : ceb;
    const ushort* Bw = (z==0) ? wqb : (z==1) ? wkb : wvb;
    const float* bias = (z==0) ? bq : (z==1) ? bk : bv;
    ushort* obf = (z==0) ? Qb : (z==1) ? Kb : Vtb;
    gemm_body(A, Bw, bias, obf, nullptr, (z==2) ? 1 : 0, blockIdx.x, blockIdx.y);
}

// O-projection (f32 out): grid (64, 6)
__global__ __launch_bounds__(256, 3) void gemm_o(
    const ushort* __restrict__ ctxb, const ushort* __restrict__ wob,
    const float* __restrict__ bo, float* __restrict__ proj)
{
    gemm_body(ctxb, wob, bo, nullptr, proj, 2, blockIdx.x, blockIdx.y);
}

// ---------------- flash attention (S^T formulation) ----------------
// grid: B*NH*8 blocks; block = (b, h, 128 q-rows); 4 waves x 32 q-rows
// lK swizzled [key][d]: chunk c of row r stored at slot c^(r&7)
// lV swizzled [d][key]: same swizzle
__global__ __launch_bounds__(256, 3) void attn(
    const ushort* __restrict__ Q, const ushort* __restrict__ Kc,
    const ushort* __restrict__ Vt, const float* __restrict__ mask,
    ushort* __restrict__ ctx)
{
    __shared__ ushort lK[64*64];
    __shared__ ushort lV[64*64];
    __shared__ ushort lP[4][32*72];
    __shared__ float  lmask[S_];
    __shared__ float  linv[4][32];

    const float SC = 0.125f * 1.44269504f;   // /sqrt(64) * log2(e)

    int bid = blockIdx.x;
    int qt = bid & 7;
    int h  = (bid >> 3) % NH_;
    int b  = bid / (8*NH_);

    int tid  = threadIdx.x;
    int lane = tid & 63, w = tid >> 6;
    int fr = lane & 15, quad = lane >> 4;
    int quad4 = quad*4, sw = fr & 7;

    for (int i = tid; i < S_; i += 256)
        lmask[i] = (1.0f - mask[b*S_ + i]) * -14426.95f;  // -10000*log2e

    // Q B-frags: 2 q n-tiles x 2 k-frags (read once from global)
    short8 qf[2][2];
    #pragma unroll
    for (int nq=0;nq<2;nq++){
        const ushort* Qp = Q + (size_t)(b*S_ + qt*128 + w*32 + nq*16 + fr)*H_ + h*HD_ + quad*8;
        qf[nq][0] = *(const short8*)(Qp);
        qf[nq][1] = *(const short8*)(Qp + 32);
    }

    floatx4 O[2][4];
    #pragma unroll
    for (int mt=0;mt<2;mt++)
        #pragma unroll
        for (int nt=0;nt<4;nt++)
            O[mt][nt] = (floatx4){0.f,0.f,0.f,0.f};
    float rs0 = 0.f, rs1 = 0.f;

    // staging: 2 rounds x 256 threads x 16B covers one 8KB tile
    int n0 = tid,       r0 = n0 >> 3, c0 = (n0 & 7) ^ (r0 & 7);
    int n1 = 256 + tid, r1 = n1 >> 3, c1 = (n1 & 7) ^ (r1 & 7);
    const ushort* pK0 = Kc + (size_t)(b*S_ + r0)*H_ + h*HD_ + c0*8;
    const ushort* pK1 = Kc + (size_t)(b*S_ + r1)*H_ + h*HD_ + c1*8;
    const ushort* pV0 = Vt + ((size_t)(b*NH_ + h)*HD_ + r0)*S_ + c0*8;
    const ushort* pV1 = Vt + ((size_t)(b*NH_ + h)*HD_ + r1)*S_ + c1*8;
    ushort* dK0 = &lK[n0*8]; ushort* dK1 = &lK[n1*8];
    ushort* dV0 = &lV[n0*8]; ushort* dV1 = &lV[n1*8];

    ushort* lPw = &lP[w][0];

    for (int kt = 0; kt < 16; kt++){
        __syncthreads();                    // prior-iter LDS reads done
        async16(pK0, dK0); async16(pK1, dK1);
        async16(pV0, dV0); async16(pV1, dV1);
        pK0 += (size_t)64*H_; pK1 += (size_t)64*H_;
        pV0 += 64; pV1 += 64;
        __syncthreads();                    // staged tiles visible

        // mask (broadcast reads, lane-uniform within quad)
        float4 mk4[4];
        #pragma unroll
        for (int mk=0;mk<4;mk++)
            mk4[mk] = *(const float4*)&lmask[kt*64 + mk*16 + quad4];

        // K A-frags (swizzled)
        short8 kf[4][2];
        #pragma unroll
        for (int mk=0;mk<4;mk++){
            int row = mk*16 + fr;
            kf[mk][0] = *(const short8*)&lK[row*64 + ((quad     ^ sw)<<3)];
            kf[mk][1] = *(const short8*)&lK[row*64 + (((4+quad) ^ sw)<<3)];
        }
        // S^T = K Q^T : C[key][q], col=lane&15=q, row=key=quad*4+r
        floatx4 st[2][4];
        #pragma unroll
        for (int nq=0;nq<2;nq++)
            #pragma unroll
            for (int mk=0;mk<4;mk++){
                floatx4 a = (floatx4){0.f,0.f,0.f,0.f};
                a = MFMA16(kf[mk][0], qf[nq][0], a);
                a = MFMA16(kf[mk][1], qf[nq][1], a);
                st[nq][mk] = a;
            }

        // exp2-softmax (no running max; masked keys underflow to 0)
        #pragma unroll
        for (int nq=0;nq<2;nq++){
            #pragma unroll
            for (int mk=0;mk<4;mk++){
                floatx4 s = st[nq][mk];
                #pragma unroll
                for (int r=0;r<4;r++)
                    s[r] = __builtin_amdgcn_exp2f(s[r]*SC + mk4[mk][r]);
                if (nq == 0) rs0 += (s[0]+s[1]) + (s[2]+s[3]);
                else         rs1 += (s[0]+s[1]) + (s[2]+s[3]);
                // pack 4 bf16 (truncate) -> one ds_write_b64 at P[q][key]
                unsigned lo = __builtin_amdgcn_perm(__float_as_uint(s[1]), __float_as_uint(s[0]), 0x07060302u);
                unsigned hi = __builtin_amdgcn_perm(__float_as_uint(s[3]), __float_as_uint(s[2]), 0x07060302u);
                uint2 pk; pk.x = lo; pk.y = hi;
                *(uint2*)&lPw[(nq*16 + fr)*72 + mk*16 + quad4] = pk;
            }
        }

        // V B-frags (swizzled) + P A-frags (wave-local LDS, compiler waits lgkm)
        short8 vf[4][2];
        #pragma unroll
        for (int nt=0;nt<4;nt++){
            int row = nt*16 + fr;
            vf[nt][0] = *(const short8*)&lV[row*64 + ((quad     ^ sw)<<3)];
            vf[nt][1] = *(const short8*)&lV[row*64 + (((4+quad) ^ sw)<<3)];
        }
        short8 pf[2][2];
        #pragma unroll
        for (int mt=0;mt<2;mt++){
            pf[mt][0] = *(const short8*)&lPw[(mt*16+fr)*72 + quad*8];
            pf[mt][1] = *(const short8*)&lPw[(mt*16+fr)*72 + 32 + quad*8];
        }
        #pragma unroll
        for (int mt=0;mt<2;mt++)
            #pragma unroll
            for (int nt=0;nt<4;nt++){
                O[mt][nt] = MFMA16(pf[mt][0], vf[nt][0], O[mt][nt]);
                O[mt][nt] = MFMA16(pf[mt][1], vf[nt][1], O[mt][nt]);
            }
    }

    // final l reduction across quads (4 shuffles total) + broadcast via LDS
    rs0 += __shfl_xor(rs0, 16); rs0 += __shfl_xor(rs0, 32);
    rs1 += __shfl_xor(rs1, 16); rs1 += __shfl_xor(rs1, 32);
    if (lane < 16){
        linv[w][fr]      = 1.0f / rs0;
        linv[w][16 + fr] = 1.0f / rs1;
    }
    // wave-local LDS; compiler inserts lgkmcnt wait before the read below
    int tokbase = b*S_ + qt*128 + w*32;
    #pragma unroll
    for (int mt=0;mt<2;mt++){
        float4 iv = *(const float4*)&linv[w][mt*16 + quad4];
        #pragma unroll
        for (int nt=0;nt<4;nt++)
            #pragma unroll
            for (int r=0;r<4;r++){
                int tok = tokbase + mt*16 + quad4 + r;
                ctx[(size_t)tok*H_ + h*HD_ + nt*16 + fr] = f2bf(O[mt][nt][r] * (&iv.x)[r]);
            }
    }
}

// ---------------- residual + LayerNorm ----------------
__global__ __launch_bounds__(256, 4) void resid_ln(
    const float* __restrict__ proj, const float* __restrict__ hs,
    const float* __restrict__ g, const float* __restrict__ be,
    float* __restrict__ out)
{
    int row = blockIdx.x;
    int tid = threadIdx.x;
    const float* p = proj + (size_t)row*H_;
    const float* x = hs   + (size_t)row*H_;
    float v[3]; float s = 0.f, s2 = 0.f;
    #pragma unroll
    for (int j=0;j<3;j++){
        float t = p[tid + j*256] + x[tid + j*256];
        v[j] = t; s += t; s2 += t*t;
    }
    #pragma unroll
    for (int off=1; off<64; off<<=1){
        s  += __shfl_xor(s,  off);
        s2 += __shfl_xor(s2, off);
    }
    __shared__ float rs[4], rs2[4];
    if ((tid & 63) == 0){ rs[tid>>6] = s; rs2[tid>>6] = s2; }
    __syncthreads();
    s  = rs[0]+rs[1]+rs[2]+rs[3];
    s2 = rs2[0]+rs2[1]+rs2[2]+rs2[3];
    float mu  = s * (1.f/H_);
    float var = s2*(1.f/H_) - mu*mu;
    float rinv = rsqrtf(var + 1e-5f);
    float* o = out + (size_t)row*H_;
    #pragma unroll
    for (int j=0;j<3;j++){
        int c = tid + j*256;
        o[c] = (v[j]-mu)*rinv*g[c] + be[c];
    }
}

extern "C" void kernel_launch(void* const* d_in, const int* in_sizes, int n_in,
                              void* d_out, int out_size, void* d_ws, size_t ws_size,
                              hipStream_t stream)
{
    (void)in_sizes; (void)n_in; (void)out_size; (void)ws_size;
    const float* hs   = (const float*)d_in[0];
    const float* ce   = (const float*)d_in[1];
    const float* mask = (const float*)d_in[2];
    const float* Wq   = (const float*)d_in[3];
    const float* bq   = (const float*)d_in[4];
    const float* Wk   = (const float*)d_in[5];
    const float* bk   = (const float*)d_in[6];
    const float* Wv   = (const float*)d_in[7];
    const float* bv   = (const float*)d_in[8];
    const float* Wo   = (const float*)d_in[9];
    const float* bo   = (const float*)d_in[10];
    const float* lg   = (const float*)d_in[11];
    const float* lb   = (const float*)d_in[12];
    float* out = (float*)d_out;

    char* ws = (char*)d_ws;
    const size_t SZ_ACT = (size_t)M_*H_*2;
    const size_t SZ_W   = (size_t)H_*H_*2;
    ushort* hsb  = (ushort*)(ws);
    ushort* ceb  = (ushort*)(ws + SZ_ACT);
    ushort* wqb  = (ushort*)(ws + 2*SZ_ACT);
    ushort* wkb  = (ushort*)(ws + 2*SZ_ACT + 1*SZ_W);
    ushort* wvb  = (ushort*)(ws + 2*SZ_ACT + 2*SZ_W);
    ushort* wob  = (ushort*)(ws + 2*SZ_ACT + 3*SZ_W);
    ushort* Qb   = (ushort*)(ws + 2*SZ_ACT + 4*SZ_W);
    ushort* Kb   = (ushort*)(ws + 3*SZ_ACT + 4*SZ_W);
    ushort* Vtb  = (ushort*)(ws + 4*SZ_ACT + 4*SZ_W);
    ushort* ctxb = (ushort*)(ws + 5*SZ_ACT + 4*SZ_W);
    float*  proj = (float*)(ws);  // aliases hsb+ceb (dead after QKV GEMMs)

    int ncvt = 2*(M_*H_/4) + 4*(H_*H_/4);   // 3,735,552
    cvt_all<<<dim3((ncvt+255)/256), dim3(256), 0, stream>>>(
        hs, ce, Wq, Wk, Wv, Wo, hsb, ceb, wqb, wkb, wvb, wob);

    gemm_qkv<<<dim3(M_/128, H_/128, 3), dim3(256), 0, stream>>>(
        hsb, ceb, wqb, wkb, wvb, bq, bk, bv, Qb, Kb, Vtb);

    attn<<<dim3(B_*NH_*8), dim3(256), 0, stream>>>(Qb, Kb, Vtb, mask, ctxb);

    gemm_o<<<dim3(M_/128, H_/128), dim3(256), 0, stream>>>(ctxb, wob, bo, proj);

    resid_ln<<<dim3(M_), dim3(256), 0, stream>>>(proj, hs, lg, lb, out);
}

// Round 3
// 229.424 us; speedup vs baseline: 1.4348x; 1.0419x over previous
//
#include <hip/hip_runtime.h>
#include <stdint.h>

#define B_ 8
#define S_ 1024
#define H_ 768
#define NH_ 12
#define HD_ 64
#define M_ (B_*S_)   // 8192 tokens

typedef __attribute__((ext_vector_type(8))) short short8;
typedef __attribute__((ext_vector_type(4))) float floatx4;

#define MFMA16(a,b,c) __builtin_amdgcn_mfma_f32_16x16x32_bf16((a),(b),(c),0,0,0)

__device__ __forceinline__ ushort f2bf(float x){
    union { float f; unsigned u; } v; v.f = x;
    unsigned r = (v.u + 0x7fffu + ((v.u >> 16) & 1u)) >> 16;
    return (ushort)r;
}

__device__ __forceinline__ void async16(const ushort* g, ushort* l){
    __builtin_amdgcn_global_load_lds(
        (const __attribute__((address_space(1))) unsigned int*)g,
        (__attribute__((address_space(3))) unsigned int*)l, 16, 0, 0);
}

// ---------------- fused f32 -> bf16 cast for all 6 tensors ----------------
__global__ __launch_bounds__(256, 8) void cvt_all(
    const float* __restrict__ hs, const float* __restrict__ ce,
    const float* __restrict__ wq, const float* __restrict__ wk,
    const float* __restrict__ wv, const float* __restrict__ wo,
    ushort* __restrict__ hsb, ushort* __restrict__ ceb,
    ushort* __restrict__ wqb, ushort* __restrict__ wkb,
    ushort* __restrict__ wvb, ushort* __restrict__ wob)
{
    const int NA = M_*H_/4;
    const int NW = H_*H_/4;
    int i = blockIdx.x*256 + threadIdx.x;
    if (i >= 2*NA + 4*NW) return;
    const float* s; ushort* d; int off;
    if (i < NA)            { s = hs; d = hsb; off = i; }
    else if (i < 2*NA)     { s = ce; d = ceb; off = i - NA; }
    else {
        int j = i - 2*NA;
        int wsel = j / NW;
        off = j - wsel*NW;
        s = (wsel==0) ? wq : (wsel==1) ? wk : (wsel==2) ? wv : wo;
        d = (wsel==0) ? wqb : (wsel==1) ? wkb : (wsel==2) ? wvb : wob;
    }
    float4 f = ((const float4*)s)[off];
    ushort4 u;
    u.x = f2bf(f.x); u.y = f2bf(f.y); u.z = f2bf(f.z); u.w = f2bf(f.w);
    ((ushort4*)d)[off] = u;
}

// ---------------- shared GEMM body: C[M,N] = A[M,K] @ B[N,K]^T + bias ------
// BK=64, XOR-swizzled 128B-pitch LDS rows (swizzle applied on global source
// column so global_load_lds keeps its linear base+lane*16 LDS mapping).
// mode 0: bf16 out [M,768]; mode 1: Vt[(b*12+h)*64+d][1024] via LDS-assembled
// coalesced stores; mode 2: f32 out.
__device__ __forceinline__ void gemm_body(
    const ushort* __restrict__ A, const ushort* __restrict__ Bw,
    const float* __restrict__ bias, ushort* __restrict__ obf,
    float* __restrict__ of32, int mode, int bx, int by)
{
    __shared__ ushort smem[16384];          // 32 KB: lA [0,8192), lB [8192,16384)
    ushort* lA = smem;
    ushort* lB = smem + 8192;
    const int K = H_;
    int tid  = threadIdx.x;
    int lane = tid & 63, wave = tid >> 6;
    int m0 = bx * 128, n0 = by * 128;
    int wm = (wave >> 1) * 64, wn = (wave & 1) * 64;
    int fr = lane & 15, quad = lane >> 4, quad4 = quad*4;

    floatx4 acc[4][4];
    #pragma unroll
    for (int mt=0;mt<4;mt++)
        #pragma unroll
        for (int nt=0;nt<4;nt++)
            acc[mt][nt] = (floatx4){0.f,0.f,0.f,0.f};

    // staging: chunk n = tid + 256*j (j=0..3); row = n>>3 (row0+32j),
    // logical col chunk c = n&7, swizzled source col = (c ^ (row&7))*8
    int row0 = tid >> 3;
    int csw  = ((tid & 7) ^ (row0 & 7)) * 8;   // same for all j (32j & 7 == 0)
    const ushort* Ap[4]; const ushort* Bp[4];
    ushort* ldA_[4]; ushort* ldB_[4];
    #pragma unroll
    for (int j=0;j<4;j++){
        int row = row0 + 32*j;
        Ap[j] = A  + (size_t)(m0 + row) * K + csw;
        Bp[j] = Bw + (size_t)(n0 + row) * K + csw;
        ldA_[j] = lA + (tid + 256*j)*8;
        ldB_[j] = lB + (tid + 256*j)*8;
    }

    for (int k0 = 0; k0 < K; k0 += 64){
        #pragma unroll
        for (int j=0;j<4;j++) async16(Ap[j] + k0, ldA_[j]);
        #pragma unroll
        for (int j=0;j<4;j++) async16(Bp[j] + k0, ldB_[j]);
        __syncthreads();
        #pragma unroll
        for (int kk=0; kk<2; kk++){
            short8 af[4], bfr[4];
            #pragma unroll
            for (int t=0;t<4;t++){
                int ra = wm + t*16 + fr;
                int rb = wn + t*16 + fr;
                af[t]  = *(const short8*)&lA[ra*64 + (((kk*4+quad) ^ (ra&7))<<3)];
                bfr[t] = *(const short8*)&lB[rb*64 + (((kk*4+quad) ^ (rb&7))<<3)];
            }
            #pragma unroll
            for (int mt=0;mt<4;mt++)
                #pragma unroll
                for (int nt=0;nt<4;nt++)
                    acc[mt][nt] = MFMA16(af[mt], bfr[nt], acc[mt][nt]);
        }
        __syncthreads();
    }

    float bv_[4];
    #pragma unroll
    for (int nt=0;nt<4;nt++) bv_[nt] = bias[n0 + wn + nt*16 + fr];

    if (mode == 0){
        #pragma unroll
        for (int mt=0;mt<4;mt++){
            int rb = m0 + wm + mt*16 + quad4;
            #pragma unroll
            for (int nt=0;nt<4;nt++){
                int col = n0 + wn + nt*16 + fr;
                #pragma unroll
                for (int r=0;r<4;r++)
                    obf[(size_t)(rb + r)*H_ + col] = f2bf(acc[mt][nt][r] + bv_[nt]);
            }
        }
    } else if (mode == 1){
        // Vt: assemble per head-half [64 d][pitch 136 q] in smem, store coalesced
        int bb = m0 >> 10, q0 = m0 & 1023;
        #pragma unroll
        for (int nh=0; nh<2; nh++){
            __syncthreads();                 // smem free (K-loop / prior half done)
            if ((wave & 1) == nh){
                #pragma unroll
                for (int mt=0;mt<4;mt++){
                    int ql = wm + mt*16 + quad4;
                    #pragma unroll
                    for (int nt=0;nt<4;nt++){
                        int dl = nt*16 + fr;
                        ushort4 u;
                        u.x = f2bf(acc[mt][nt][0] + bv_[nt]);
                        u.y = f2bf(acc[mt][nt][1] + bv_[nt]);
                        u.z = f2bf(acc[mt][nt][2] + bv_[nt]);
                        u.w = f2bf(acc[mt][nt][3] + bv_[nt]);
                        *(ushort4*)&smem[dl*136 + ql] = u;
                    }
                }
            }
            __syncthreads();
            int head = by*2 + nh;
            #pragma unroll
            for (int jj=0;jj<4;jj++){
                int mI = tid + 256*jj;       // 0..1023
                int d  = mI >> 4;            // 0..63
                int qc = (mI & 15) * 8;      // 0..120
                short8 v = *(const short8*)&smem[d*136 + qc];
                *(short8*)&obf[((size_t)((bb*NH_ + head)*HD_ + d))*S_ + q0 + qc] = v;
            }
        }
    } else {
        #pragma unroll
        for (int mt=0;mt<4;mt++){
            int rb = m0 + wm + mt*16 + quad4;
            #pragma unroll
            for (int nt=0;nt<4;nt++){
                int col = n0 + wn + nt*16 + fr;
                #pragma unroll
                for (int r=0;r<4;r++)
                    of32[(size_t)(rb + r)*H_ + col] = acc[mt][nt][r] + bv_[nt];
            }
        }
    }
}

// fused Q/K/V projection: grid (64, 6, 3)
__global__ __launch_bounds__(256, 3) void gemm_qkv(
    const ushort* __restrict__ hsb, const ushort* __restrict__ ceb,
    const ushort* __restrict__ wqb, const ushort* __restrict__ wkb,
    const ushort* __restrict__ wvb,
    const float* __restrict__ bq, const float* __restrict__ bk,
    const float* __restrict__ bv,
    ushort* __restrict__ Qb, ushort* __restrict__ Kb, ushort* __restrict__ Vtb)
{
    int z = blockIdx.z;
    const ushort* A  = (z==0) ? hsb : ceb;
    const ushort* Bw = (z==0) ? wqb : (z==1) ? wkb : wvb;
    const float* bias = (z==0) ? bq : (z==1) ? bk : bv;
    ushort* obf = (z==0) ? Qb : (z==1) ? Kb : Vtb;
    gemm_body(A, Bw, bias, obf, nullptr, (z==2) ? 1 : 0, blockIdx.x, blockIdx.y);
}

// O-projection (f32 out): grid (64, 6)
__global__ __launch_bounds__(256, 3) void gemm_o(
    const ushort* __restrict__ ctxb, const ushort* __restrict__ wob,
    const float* __restrict__ bo, float* __restrict__ proj)
{
    gemm_body(ctxb, wob, bo, nullptr, proj, 2, blockIdx.x, blockIdx.y);
}

// ---------------- flash attention (S^T formulation) ----------------
// grid: B*NH*8 blocks; block = (b, h, 128 q-rows); 4 waves x 32 q-rows
__global__ __launch_bounds__(256, 3) void attn(
    const ushort* __restrict__ Q, const ushort* __restrict__ Kc,
    const ushort* __restrict__ Vt, const float* __restrict__ mask,
    ushort* __restrict__ ctx)
{
    __shared__ ushort lK[64*64];
    __shared__ ushort lV[64*64];
    __shared__ ushort lP[4][32*72];
    __shared__ float  lmask[S_];
    __shared__ float  linv[4][32];

    const float SC = 0.125f * 1.44269504f;

    int bid = blockIdx.x;
    int qt = bid & 7;
    int h  = (bid >> 3) % NH_;
    int b  = bid / (8*NH_);

    int tid  = threadIdx.x;
    int lane = tid & 63, w = tid >> 6;
    int fr = lane & 15, quad = lane >> 4;
    int quad4 = quad*4, sw = fr & 7;

    for (int i = tid; i < S_; i += 256)
        lmask[i] = (1.0f - mask[b*S_ + i]) * -14426.95f;

    short8 qf[2][2];
    #pragma unroll
    for (int nq=0;nq<2;nq++){
        const ushort* Qp = Q + (size_t)(b*S_ + qt*128 + w*32 + nq*16 + fr)*H_ + h*HD_ + quad*8;
        qf[nq][0] = *(const short8*)(Qp);
        qf[nq][1] = *(const short8*)(Qp + 32);
    }

    floatx4 O[2][4];
    #pragma unroll
    for (int mt=0;mt<2;mt++)
        #pragma unroll
        for (int nt=0;nt<4;nt++)
            O[mt][nt] = (floatx4){0.f,0.f,0.f,0.f};
    float rs0 = 0.f, rs1 = 0.f;

    int n0 = tid,       r0 = n0 >> 3, c0 = (n0 & 7) ^ (r0 & 7);
    int n1 = 256 + tid, r1 = n1 >> 3, c1 = (n1 & 7) ^ (r1 & 7);
    const ushort* pK0 = Kc + (size_t)(b*S_ + r0)*H_ + h*HD_ + c0*8;
    const ushort* pK1 = Kc + (size_t)(b*S_ + r1)*H_ + h*HD_ + c1*8;
    const ushort* pV0 = Vt + ((size_t)(b*NH_ + h)*HD_ + r0)*S_ + c0*8;
    const ushort* pV1 = Vt + ((size_t)(b*NH_ + h)*HD_ + r1)*S_ + c1*8;
    ushort* dK0 = &lK[n0*8]; ushort* dK1 = &lK[n1*8];
    ushort* dV0 = &lV[n0*8]; ushort* dV1 = &lV[n1*8];

    ushort* lPw = &lP[w][0];

    for (int kt = 0; kt < 16; kt++){
        __syncthreads();
        async16(pK0, dK0); async16(pK1, dK1);
        async16(pV0, dV0); async16(pV1, dV1);
        pK0 += (size_t)64*H_; pK1 += (size_t)64*H_;
        pV0 += 64; pV1 += 64;
        __syncthreads();

        float4 mk4[4];
        #pragma unroll
        for (int mk=0;mk<4;mk++)
            mk4[mk] = *(const float4*)&lmask[kt*64 + mk*16 + quad4];

        short8 kf[4][2];
        #pragma unroll
        for (int mk=0;mk<4;mk++){
            int row = mk*16 + fr;
            kf[mk][0] = *(const short8*)&lK[row*64 + ((quad     ^ sw)<<3)];
            kf[mk][1] = *(const short8*)&lK[row*64 + (((4+quad) ^ sw)<<3)];
        }
        floatx4 st[2][4];
        #pragma unroll
        for (int nq=0;nq<2;nq++)
            #pragma unroll
            for (int mk=0;mk<4;mk++){
                floatx4 a = (floatx4){0.f,0.f,0.f,0.f};
                a = MFMA16(kf[mk][0], qf[nq][0], a);
                a = MFMA16(kf[mk][1], qf[nq][1], a);
                st[nq][mk] = a;
            }

        #pragma unroll
        for (int nq=0;nq<2;nq++){
            #pragma unroll
            for (int mk=0;mk<4;mk++){
                floatx4 s = st[nq][mk];
                #pragma unroll
                for (int r=0;r<4;r++)
                    s[r] = __builtin_amdgcn_exp2f(s[r]*SC + mk4[mk][r]);
                if (nq == 0) rs0 += (s[0]+s[1]) + (s[2]+s[3]);
                else         rs1 += (s[0]+s[1]) + (s[2]+s[3]);
                unsigned lo = __builtin_amdgcn_perm(__float_as_uint(s[1]), __float_as_uint(s[0]), 0x07060302u);
                unsigned hi = __builtin_amdgcn_perm(__float_as_uint(s[3]), __float_as_uint(s[2]), 0x07060302u);
                uint2 pk; pk.x = lo; pk.y = hi;
                *(uint2*)&lPw[(nq*16 + fr)*72 + mk*16 + quad4] = pk;
            }
        }

        short8 vf[4][2];
        #pragma unroll
        for (int nt=0;nt<4;nt++){
            int row = nt*16 + fr;
            vf[nt][0] = *(const short8*)&lV[row*64 + ((quad     ^ sw)<<3)];
            vf[nt][1] = *(const short8*)&lV[row*64 + (((4+quad) ^ sw)<<3)];
        }
        short8 pf[2][2];
        #pragma unroll
        for (int mt=0;mt<2;mt++){
            pf[mt][0] = *(const short8*)&lPw[(mt*16+fr)*72 + quad*8];
            pf[mt][1] = *(const short8*)&lPw[(mt*16+fr)*72 + 32 + quad*8];
        }
        #pragma unroll
        for (int mt=0;mt<2;mt++)
            #pragma unroll
            for (int nt=0;nt<4;nt++){
                O[mt][nt] = MFMA16(pf[mt][0], vf[nt][0], O[mt][nt]);
                O[mt][nt] = MFMA16(pf[mt][1], vf[nt][1], O[mt][nt]);
            }
    }

    rs0 += __shfl_xor(rs0, 16); rs0 += __shfl_xor(rs0, 32);
    rs1 += __shfl_xor(rs1, 16); rs1 += __shfl_xor(rs1, 32);
    if (lane < 16){
        linv[w][fr]      = 1.0f / rs0;
        linv[w][16 + fr] = 1.0f / rs1;
    }
    int tokbase = b*S_ + qt*128 + w*32;
    #pragma unroll
    for (int mt=0;mt<2;mt++){
        float4 iv = *(const float4*)&linv[w][mt*16 + quad4];
        #pragma unroll
        for (int nt=0;nt<4;nt++)
            #pragma unroll
            for (int r=0;r<4;r++){
                int tok = tokbase + mt*16 + quad4 + r;
                ctx[(size_t)tok*H_ + h*HD_ + nt*16 + fr] = f2bf(O[mt][nt][r] * (&iv.x)[r]);
            }
    }
}

// ---------------- residual + LayerNorm ----------------
__global__ __launch_bounds__(256, 4) void resid_ln(
    const float* __restrict__ proj, const float* __restrict__ hs,
    const float* __restrict__ g, const float* __restrict__ be,
    float* __restrict__ out)
{
    int row = blockIdx.x;
    int tid = threadIdx.x;
    const float* p = proj + (size_t)row*H_;
    const float* x = hs   + (size_t)row*H_;
    float v[3]; float s = 0.f, s2 = 0.f;
    #pragma unroll
    for (int j=0;j<3;j++){
        float t = p[tid + j*256] + x[tid + j*256];
        v[j] = t; s += t; s2 += t*t;
    }
    #pragma unroll
    for (int off=1; off<64; off<<=1){
        s  += __shfl_xor(s,  off);
        s2 += __shfl_xor(s2, off);
    }
    __shared__ float rs[4], rs2[4];
    if ((tid & 63) == 0){ rs[tid>>6] = s; rs2[tid>>6] = s2; }
    __syncthreads();
    s  = rs[0]+rs[1]+rs[2]+rs[3];
    s2 = rs2[0]+rs2[1]+rs2[2]+rs2[3];
    float mu  = s * (1.f/H_);
    float var = s2*(1.f/H_) - mu*mu;
    float rinv = rsqrtf(var + 1e-5f);
    float* o = out + (size_t)row*H_;
    #pragma unroll
    for (int j=0;j<3;j++){
        int c = tid + j*256;
        o[c] = (v[j]-mu)*rinv*g[c] + be[c];
    }
}

extern "C" void kernel_launch(void* const* d_in, const int* in_sizes, int n_in,
                              void* d_out, int out_size, void* d_ws, size_t ws_size,
                              hipStream_t stream)
{
    (void)in_sizes; (void)n_in; (void)out_size; (void)ws_size;
    const float* hs   = (const float*)d_in[0];
    const float* ce   = (const float*)d_in[1];
    const float* mask = (const float*)d_in[2];
    const float* Wq   = (const float*)d_in[3];
    const float* bq   = (const float*)d_in[4];
    const float* Wk   = (const float*)d_in[5];
    const float* bk   = (const float*)d_in[6];
    const float* Wv   = (const float*)d_in[7];
    const float* bv   = (const float*)d_in[8];
    const float* Wo   = (const float*)d_in[9];
    const float* bo   = (const float*)d_in[10];
    const float* lg   = (const float*)d_in[11];
    const float* lb   = (const float*)d_in[12];
    float* out = (float*)d_out;

    char* ws = (char*)d_ws;
    const size_t SZ_ACT = (size_t)M_*H_*2;
    const size_t SZ_W   = (size_t)H_*H_*2;
    ushort* hsb  = (ushort*)(ws);
    ushort* ceb  = (ushort*)(ws + SZ_ACT);
    ushort* wqb  = (ushort*)(ws + 2*SZ_ACT);
    ushort* wkb  = (ushort*)(ws + 2*SZ_ACT + 1*SZ_W);
    ushort* wvb  = (ushort*)(ws + 2*SZ_ACT + 2*SZ_W);
    ushort* wob  = (ushort*)(ws + 2*SZ_ACT + 3*SZ_W);
    ushort* Qb   = (ushort*)(ws + 2*SZ_ACT + 4*SZ_W);
    ushort* Kb   = (ushort*)(ws + 3*SZ_ACT + 4*SZ_W);
    ushort* Vtb  = (ushort*)(ws + 4*SZ_ACT + 4*SZ_W);
    ushort* ctxb = (ushort*)(ws + 5*SZ_ACT + 4*SZ_W);
    float*  proj = (float*)(ws);  // aliases hsb+ceb (dead after QKV GEMMs)

    int ncvt = 2*(M_*H_/4) + 4*(H_*H_/4);
    cvt_all<<<dim3((ncvt+255)/256), dim3(256), 0, stream>>>(
        hs, ce, Wq, Wk, Wv, Wo, hsb, ceb, wqb, wkb, wvb, wob);

    gemm_qkv<<<dim3(M_/128, H_/128, 3), dim3(256), 0, stream>>>(
        hsb, ceb, wqb, wkb, wvb, bq, bk, bv, Qb, Kb, Vtb);

    attn<<<dim3(B_*NH_*8), dim3(256), 0, stream>>>(Qb, Kb, Vtb, mask, ctxb);

    gemm_o<<<dim3(M_/128, H_/128), dim3(256), 0, stream>>>(ctxb, wob, bo, proj);

    resid_ln<<<dim3(M_), dim3(256), 0, stream>>>(proj, hs, lg, lb, out);
}